// Round 16
// baseline (108.249 us; speedup 1.0000x reference)
//
#include <hip/hip_runtime.h>
#include <math.h>

constexpr int B = 16, F = 64, E = 16, H = 64, W = 64;
constexpr int XP = 66;          // xTs padded x dim (1 zero col each side)
constexpr int XW = 36;          // staged input cols per block (32 + halos)
constexpr int CPL = 72;         // s_in/sxo inner pad (16B-aligned bf16x8 rows)
constexpr int SPPL = 40;        // s_sp inner pad (bf16, 16B-aligned rows)
constexpr int YSTRIDE = XP * F; // 4224 elems per (b,y) row in xTs

typedef __bf16 bf16x8 __attribute__((ext_vector_type(8)));
typedef __bf16 bf16x4 __attribute__((ext_vector_type(4)));
typedef float f32x16 __attribute__((ext_vector_type(16)));
typedef float f32x4 __attribute__((ext_vector_type(4)));

// ---------------------------------------------------------------------------
// prep (unchanged from R14): transpose state -> xTs bf16; fragment-major
// weight repack (wA1f/wA2f/wT3bf); zero d_out accumulator region.
// ---------------------------------------------------------------------------
__global__ __launch_bounds__(256) void prep_kernel(
    const float* __restrict__ state, const float* __restrict__ pre_w,
    const float* __restrict__ attn_w, const float* __restrict__ c3_w,
    __bf16* __restrict__ xTs, __bf16* __restrict__ wA1f,
    __bf16* __restrict__ wA2f, __bf16* __restrict__ wT3bf,
    float* __restrict__ out0)
{
    __shared__ float s_t[64][68];
    const int blk = blockIdx.x;
    const int tid = threadIdx.x;

    if (blk < 1024) {
        const int b = blk >> 6, y = blk & 63;
        {
            int c = tid >> 2, x0 = (tid & 3) * 16;
            const float* src = state + ((size_t)(b * F + c) * H + y) * W + x0;
            #pragma unroll
            for (int q = 0; q < 4; ++q)
                *(float4*)&s_t[c][x0 + 4 * q] = *(const float4*)(src + 4 * q);
        }
        __syncthreads();
        __bf16* dst = xTs + (size_t)(b * H + y) * YSTRIDE;
        #pragma unroll
        for (int i = 0; i < 2; ++i) {
            int t = tid + i * 256;
            int x = t >> 3, cg = t & 7;
            bf16x8 v;
            #pragma unroll
            for (int j = 0; j < 8; ++j) v[j] = (__bf16)s_t[cg * 8 + j][x];
            *(bf16x8*)(dst + (x + 1) * F + cg * 8) = v;
        }
        if (tid < 16) {
            int bd = tid >> 3, cg = tid & 7;
            bf16x8 z = {};
            *(bf16x8*)(dst + (bd ? 65 : 0) * F + cg * 8) = z;
        }
    } else if (blk < 1168) {
        int idx = (blk - 1024) * 256 + tid;
        {   // wA1f[t9][cq][mt][kh][n][8]: 36864 elems (144 blocks x 256)
            int j = idx & 7, n = (idx >> 3) & 31, kh = (idx >> 8) & 1;
            int mt = (idx >> 9) & 1, cq = (idx >> 10) & 3, t9 = idx >> 12;
            int o = mt * 32 + n, c = cq * 16 + kh * 8 + j;
            wA1f[idx] = (__bf16)pre_w[(o * 64 + c) * 9 + t9];
        }
        if (idx < 9216) {  // wA2f[t9][cq][quad][n16][8]
            int j = idx & 7, n16 = (idx >> 3) & 15, quad = (idx >> 7) & 3;
            int cq = (idx >> 9) & 1, t9 = idx >> 10;
            int c = cq * 32 + quad * 8 + j;
            wA2f[idx] = (__bf16)attn_w[(n16 * 64 + c) * 9 + t9];
        }
        if (idx < 4096) {  // wT3bf[cq][mt][kh][n][8]
            int j = idx & 7, n = (idx >> 3) & 31, kh = (idx >> 8) & 1;
            int mt = (idx >> 9) & 1, cq = idx >> 10;
            wT3bf[idx] = (__bf16)c3_w[(mt * 32 + n) * 64 + cq * 16 + kh * 8 + j];
        }
    } else {
        int idx = (blk - 1168) * 256 + tid;  // 16 blocks cover 16384 floats
        float4 z = {0.f, 0.f, 0.f, 0.f};
        *(float4*)(out0 + idx * 4) = z;
    }
}

// ---------------------------------------------------------------------------
// mega v9b: x-split for occupancy (R15 + race fix: border zeros folded into
// the conv1 epilogue mask; the separate zeroing block that raced with the
// overlapping-tile writes is gone).
// block = (b, yp 2-rows, xh 32-col half); 1024 blocks x 256 thr; LDS ~35 KB
// -> 4 blocks/CU (16 waves/CU).
// ---------------------------------------------------------------------------
__global__ __launch_bounds__(256, 4) void mega_kernel(
    const __bf16* __restrict__ xTs, const __bf16* __restrict__ wA1f,
    const __bf16* __restrict__ wA2f, const __bf16* __restrict__ wT3bf,
    const float* __restrict__ pre_b, const float* __restrict__ attn_b,
    const float* __restrict__ c3_b,
    float* __restrict__ attn_out, float* __restrict__ out)
{
    __shared__ __align__(16) char smem[35072];
    const int b = blockIdx.y;
    const int yp = blockIdx.x >> 1, xh = blockIdx.x & 1;
    const int tid = threadIdx.x;
    const int wave = tid >> 6, lane = tid & 63;
    const int y0 = yp * 2, xh0 = xh * 32;

    __bf16* s_in = (__bf16*)smem;                        // [6][XW][CPL] 31104 B
    __bf16* sxo  = (__bf16*)smem;                        // [4][XW][CPL] 20736 B (overlay)
    __bf16* s_sp = (__bf16*)(smem + 20736);              // [2][64][SPPL] 10240 B
    float (*s_attn)[32][16] = (float(*)[32][16])(smem + 30976);  // 4096 B

    // ---------- stage 6 rows x 36 cols (coalesced; OOB -> zero) ----------
    for (int t = tid; t < 6 * XW * 8; t += 256) {
        int r = t / (XW * 8), rem = t - r * (XW * 8);
        int l = rem >> 3, cg = rem & 7;
        int yy = y0 - 2 + r;
        int xc = xh0 - 1 + l;            // xTs column index
        bf16x8 v = {};
        if ((unsigned)yy < (unsigned)H && (unsigned)xc < (unsigned)XP)
            v = *(const bf16x8*)(xTs + (size_t)(b * H + yy) * YSTRIDE + xc * F + cg * 8);
        *(bf16x8*)(s_in + (r * XW + l) * CPL + cg * 8) = v;
    }
    __syncthreads();   // B1

    const int n = lane & 31, kh = lane >> 5;

    // ---------- conv1: wave = row r1; out row yr = y0-1+r1; 2 x-tiles ----------
    // tile t: sxo index s = 2t+n  <->  conv1 global col xh0 + s - 1
    const int r1 = wave;
    const int yr = y0 - 1 + r1;
    const bool valid = (yr >= 0 && yr < H);
    f32x16 acc[4] = {};   // [t*2+mt]
    if (valid) {
        #pragma unroll
        for (int dy = 0; dy < 3; ++dy) {
            #pragma unroll
            for (int dx = 0; dx < 3; ++dx) {
                const int t9 = dy * 3 + dx;
                const __bf16* aB = wA1f + t9 * 4096 + kh * 256 + n * 8;
                const __bf16* bB = s_in + ((r1 + dy) * XW + (n + dx)) * CPL + kh * 8;
                #pragma unroll
                for (int cq = 0; cq < 4; ++cq) {
                    bf16x8 a0 = *(const bf16x8*)(aB + cq * 1024);          // mt=0
                    bf16x8 a1 = *(const bf16x8*)(aB + cq * 1024 + 512);    // mt=1
                    bf16x8 b0 = *(const bf16x8*)(bB + cq * 16);            // tile0
                    bf16x8 b1 = *(const bf16x8*)(bB + 2 * CPL + cq * 16);  // tile1 (+2 cols)
                    acc[0] = __builtin_amdgcn_mfma_f32_32x32x16_bf16(a0, b0, acc[0], 0, 0, 0);
                    acc[1] = __builtin_amdgcn_mfma_f32_32x32x16_bf16(a1, b0, acc[1], 0, 0, 0);
                    acc[2] = __builtin_amdgcn_mfma_f32_32x32x16_bf16(a0, b1, acc[2], 0, 0, 0);
                    acc[3] = __builtin_amdgcn_mfma_f32_32x32x16_bf16(a1, b1, acc[3], 0, 0, 0);
                }
            }
        }
    }

    // ---------- sproj: wave = (mt_s, rr_s); B from s_in rows 2,3 ----------
    const int mt_s = wave & 1, rr_s = wave >> 1;
    f32x16 accsp = {};
    #pragma unroll
    for (int cq = 0; cq < 4; ++cq) {
        bf16x8 a  = *(const bf16x8*)(wT3bf + cq * 1024 + mt_s * 512 + kh * 256 + n * 8);
        bf16x8 bb = *(const bf16x8*)(s_in + ((2 + rr_s) * XW + n + 2) * CPL
                                     + cq * 16 + kh * 8);
        accsp = __builtin_amdgcn_mfma_f32_32x32x16_bf16(a, bb, accsp, 0, 0, 0);
    }
    __syncthreads();   // B2: s_in reads done; overlays writable

    // ---------- conv1 epilogue -> sxo (border zeros folded into the mask);
    //            sproj epilogue -> s_sp ----------
    {
        __bf16* orow = sxo + r1 * XW * CPL;
        #pragma unroll
        for (int t = 0; t < 2; ++t) {
            // tile0 lane0 @ xh0-1 (xh==0 -> global -1) and tile1 lane31 @
            // xh0+32 (xh==1 -> global 64) are the zero-pad columns.
            const bool edge = (t == 0) ? (xh == 0 && n == 0)
                                       : (xh == 1 && n == 31);
            const bool wr = valid && !edge;
            #pragma unroll
            for (int mt2 = 0; mt2 < 2; ++mt2)
                #pragma unroll
                for (int g = 0; g < 4; ++g) {
                    int o0 = mt2 * 32 + kh * 4 + g * 8;
                    f32x4 b4 = *(const f32x4*)(pre_b + o0);
                    bf16x4 v0 = {};
                    if (wr) {
                        #pragma unroll
                        for (int r = 0; r < 4; ++r)
                            v0[r] = (__bf16)fmaxf(acc[t * 2 + mt2][g * 4 + r] + b4[r], 0.f);
                    }
                    *(bf16x4*)(orow + (2 * t + n) * CPL + o0) = v0;
                }
        }
        // sproj D: o = mt_s*32+kh*4+g*8+r, p = n  -> s_sp[rr_s][o][p]
        #pragma unroll
        for (int g = 0; g < 4; ++g)
            #pragma unroll
            for (int r = 0; r < 4; ++r) {
                int o = mt_s * 32 + kh * 4 + g * 8 + r;
                s_sp[(rr_s * 64 + o) * SPPL + n] = (__bf16)accsp[g * 4 + r];
            }
    }
    __syncthreads();   // B3

    // ---------- conv2: wave = (rw = wave>>1, xq = wave&1); N=16 ----------
    {
        const int rw = wave >> 1, xq = wave & 1;
        const int n16 = lane & 15, quad = lane >> 4;
        f32x4 acc2 = {};
        #pragma unroll
        for (int dy = 0; dy < 3; ++dy)
            #pragma unroll
            for (int dx = 0; dx < 3; ++dx) {
                const int t9 = dy * 3 + dx;
                #pragma unroll
                for (int cq = 0; cq < 2; ++cq) {
                    bf16x8 a = *(const bf16x8*)(wA2f + ((t9 * 2 + cq) * 4 + quad) * 128
                                                + n16 * 8);
                    const __bf16* bp = sxo +
                        ((rw + dy) * XW + (xq * 16 + n16 + dx)) * CPL + quad * 8 + cq * 32;
                    acc2 = __builtin_amdgcn_mfma_f32_16x16x32_bf16(
                        a, *(const bf16x8*)bp, acc2, 0, 0, 0);
                }
            }
        const int xl = xq * 16 + n16;
        #pragma unroll
        for (int r = 0; r < 4; ++r) {
            int e = quad * 4 + r;
            float val = acc2[r] + attn_b[e];
            float sg = 1.f / (1.f + __expf(-val));
            attn_out[((size_t)(b * E + e) * H + (y0 + rw)) * W + xh0 + xl] = sg;
            s_attn[rw][xl][e] = sg;   // disjoint region; no extra sync
        }
    }
    __syncthreads();   // B4

    // ---------- reduce: thread = (o = tid&63, eg = tid>>6), 32 px x 2 rows ---
    {
        const int o = tid & 63, eg = tid >> 6;
        const float cb = c3_b[o];
        float accl[4] = {0.f, 0.f, 0.f, 0.f};
        #pragma unroll
        for (int rr = 0; rr < 2; ++rr) {
            const __bf16* spr = s_sp + (rr * 64 + o) * SPPL;
            #pragma unroll
            for (int pb = 0; pb < 4; ++pb) {
                bf16x8 sp8 = *(const bf16x8*)(spr + pb * 8);
                #pragma unroll
                for (int k = 0; k < 8; ++k) {
                    float spf = (float)sp8[k];
                    f32x4 a4 = *(const f32x4*)&s_attn[rr][pb * 8 + k][eg * 4];
                    #pragma unroll
                    for (int i = 0; i < 4; ++i)
                        accl[i] += fmaxf(fmaf(a4[i], spf, cb), 0.f);
                }
            }
        }
        const float border = (blockIdx.x == 0) ? 260.f * fmaxf(cb, 0.f) : 0.f;
        #pragma unroll
        for (int i = 0; i < 4; ++i) {
            int e = eg * 4 + i;
            atomicAdd(&out[(b * E + e) * F + o], (accl[i] + border) * (1.f / 4356.f));
        }
    }
}

// ---------------------------------------------------------------------------
extern "C" void kernel_launch(void* const* d_in, const int* in_sizes, int n_in,
                              void* d_out, int out_size, void* d_ws, size_t ws_size,
                              hipStream_t stream) {
    (void)in_sizes; (void)n_in; (void)out_size; (void)ws_size;
    const float* state  = (const float*)d_in[0];
    const float* pre_w  = (const float*)d_in[1];
    const float* pre_b  = (const float*)d_in[2];
    const float* attn_w = (const float*)d_in[3];
    const float* attn_b = (const float*)d_in[4];
    const float* c3_w   = (const float*)d_in[5];
    const float* c3_b   = (const float*)d_in[6];

    float* out      = (float*)d_out;
    float* attn_out = out + B * E * F;

    char* ws = (char*)d_ws;
    constexpr size_t XT_BYTES = (size_t)B * H * YSTRIDE * 2;   // 8,650,752
    __bf16* xTs   = (__bf16*)ws;
    __bf16* wA1f  = (__bf16*)(ws + XT_BYTES);
    __bf16* wA2f  = (__bf16*)(ws + XT_BYTES + 73728);
    __bf16* wT3bf = (__bf16*)(ws + XT_BYTES + 73728 + 18432);

    prep_kernel<<<1184, 256, 0, stream>>>(state, pre_w, attn_w, c3_w,
                                          xTs, wA1f, wA2f, wT3bf, out);
    mega_kernel<<<dim3(64, B), 256, 0, stream>>>(xTs, wA1f, wA2f, wT3bf,
                                                 pre_b, attn_b, c3_b,
                                                 attn_out, out);
}